// Round 9
// baseline (604.870 us; speedup 1.0000x reference)
//
#include <hip/hip_runtime.h>
#include <math.h>

#define NATOMS  4096
#define FDIM    128
#define NHEAD   4
#define DHEAD   32
#define KNBR    15
#define NKER    50
#define NLAYER  6
#define QKVW    640   // 128 q + 128 k + 384 v
#define LISTCAP 768
#define FB      385   // fbuf row stride (384 val cols + 1 pad)

typedef __attribute__((ext_vector_type(8))) short short8;
typedef __attribute__((ext_vector_type(4))) float f32x4;

__device__ __forceinline__ float silu_f(float x) { return x / (1.0f + __expf(-x)); }

__device__ __forceinline__ unsigned long long shfl_xor_u64(unsigned long long v, int m) {
    unsigned lo = (unsigned)v, hi = (unsigned)(v >> 32);
    lo = (unsigned)__shfl_xor((int)lo, m);
    hi = (unsigned)__shfl_xor((int)hi, m);
    return ((unsigned long long)hi << 32) | lo;
}
__device__ __forceinline__ unsigned long long min_u64(unsigned long long a, unsigned long long b) {
    return a < b ? a : b;
}
__device__ __forceinline__ int spread3(int v) {   // 4 bits -> bits 0,3,6,9
    return (v & 1) | ((v & 2) << 2) | ((v & 4) << 4) | ((v & 8) << 6);
}

// ---------------------------------------------------------------------------
// Kernel 0: Morton counting-sort -> perm, sorted coords/batch, cell CSR
// ---------------------------------------------------------------------------
__global__ __launch_bounds__(1024) void morton_kernel(
    const float* __restrict__ R, const float* __restrict__ batch,
    int* __restrict__ perm, float* __restrict__ Rs,
    float* __restrict__ batch_s, int* __restrict__ cell_start)
{
    __shared__ int hist[4096];
    __shared__ int tscan[1024];
    const int t = threadIdx.x;
    int codes[4];
    float xs[4], ys[4], zs[4];
    #pragma unroll
    for (int u = 0; u < 4; ++u) hist[t*4 + u] = 0;
    __syncthreads();
    #pragma unroll
    for (int u = 0; u < 4; ++u) {
        int i = t + u*1024;
        float x = R[i*3+0], y = R[i*3+1], z = R[i*3+2];
        xs[u] = x; ys[u] = y; zs[u] = z;
        int cx = min(15, max(0, (int)(x * 0.4f)));
        int cy = min(15, max(0, (int)(y * 0.4f)));
        int cz = min(15, max(0, (int)(z * 0.4f)));
        int code = spread3(cx) | (spread3(cy) << 1) | (spread3(cz) << 2);
        codes[u] = code;
        atomicAdd(&hist[code], 1);
    }
    __syncthreads();
    int loc[4], s0 = 0;
    #pragma unroll
    for (int u = 0; u < 4; ++u) { loc[u] = hist[t*4 + u]; s0 += loc[u]; }
    tscan[t] = s0;
    __syncthreads();
    for (int off = 1; off < 1024; off <<= 1) {
        int v = tscan[t];
        int a = (t >= off) ? tscan[t - off] : 0;
        __syncthreads();
        tscan[t] = v + a;
        __syncthreads();
    }
    int run = tscan[t] - s0;
    #pragma unroll
    for (int u = 0; u < 4; ++u) {
        hist[t*4 + u] = run;
        cell_start[t*4 + u] = run;
        run += loc[u];
    }
    if (t == 0) cell_start[4096] = NATOMS;
    __syncthreads();
    #pragma unroll
    for (int u = 0; u < 4; ++u) {
        int i = t + u*1024;
        int r = atomicAdd(&hist[codes[u]], 1);
        perm[r] = i;
        Rs[r*3+0] = xs[u]; Rs[r*3+1] = ys[u]; Rs[r*3+2] = zs[u];
        batch_s[r] = batch[i];
    }
}

// ---------------------------------------------------------------------------
// Kernel 1: cell-list KNN, one wave per atom; bakes eA (bf16 hi/lo A-frags)
// ---------------------------------------------------------------------------
__global__ __launch_bounds__(64) void knn_kernel(
    const float* __restrict__ Rs, const float* __restrict__ batch_s,
    const int* __restrict__ cell_start,
    int* __restrict__ idxs, float* __restrict__ cutw,
    float* __restrict__ vecn, unsigned short* __restrict__ eA)
{
    __shared__ unsigned long long list[LISTCAP];
    __shared__ int   ridx[LISTCAP];
    __shared__ float e_lds[16][68];
    __shared__ float dist[KNBR];
    __shared__ float cutl[KNBR];
    __shared__ int   selr[KNBR];
    __shared__ int   cnt;
    const int r = blockIdx.x, t = threadIdx.x;
    if (t == 0) cnt = 0;
    for (int x = t; x < 16*68; x += 64) ((float*)e_lds)[x] = 0.0f;
    const float xi = Rs[r*3+0], yi = Rs[r*3+1], zi = Rs[r*3+2];
    const float bi = batch_s[r];
    const float sqi = xi*xi + yi*yi + zi*zi;
    const int cx = min(15, max(0, (int)(xi * 0.4f)));
    const int cy = min(15, max(0, (int)(yi * 0.4f)));
    const int cz = min(15, max(0, (int)(zi * 0.4f)));
    __syncthreads();

    for (int cid = t; cid < 343; cid += 64) {
        int nx = cx + (cid % 7) - 3;
        int ny = cy + ((cid / 7) % 7) - 3;
        int nz = cz + (cid / 49) - 3;
        if (nx < 0 || nx > 15 || ny < 0 || ny > 15 || nz < 0 || nz > 15) continue;
        int code = spread3(nx) | (spread3(ny) << 1) | (spread3(nz) << 2);
        int s0 = cell_start[code], s1 = cell_start[code + 1];
        for (int r2 = s0; r2 < s1; ++r2) {
            if (r2 == r) continue;
            float xj = Rs[r2*3+0], yj = Rs[r2*3+1], zj = Rs[r2*3+2];
            if (bi * batch_s[r2] == 0.0f) continue;
            float sqj = xj*xj + yj*yj + zj*zj;
            float d2 = sqi + sqj - 2.0f*(xi*xj + yi*yj + zi*zj);
            d2 = fmaxf(d2, 0.0f);
            int slot = atomicAdd(&cnt, 1);
            if (slot < LISTCAP) {
                list[slot] = ((unsigned long long)__float_as_uint(d2) << 32) | (unsigned)slot;
                ridx[slot] = r2;
            }
        }
    }
    __syncthreads();
    const int n = min(cnt, LISTCAP);

    unsigned long long cand = ~0ull;
    for (int idx = t; idx < n; idx += 64) cand = min_u64(cand, list[idx]);
    for (int k = 0; k < KNBR; ++k) {
        unsigned long long w = cand;
        #pragma unroll
        for (int off = 1; off < 64; off <<= 1)
            w = min_u64(w, shfl_xor_u64(w, off));
        int slot = (int)(unsigned)w;
        if (t == 0) selr[k] = ridx[slot];
        if ((slot & 63) == t) {
            list[slot] = ~0ull;
            cand = ~0ull;
            for (int idx = t; idx < n; idx += 64) cand = min_u64(cand, list[idx]);
        }
        __syncthreads();
    }

    if (t < KNBR) {
        int r2 = selr[t];
        idxs[r*KNBR + t] = r2;
        float vx = Rs[r2*3+0]-xi, vy = Rs[r2*3+1]-yi, vz = Rs[r2*3+2]-zi;
        float d = sqrtf(vx*vx + vy*vy + vz*vz + 1e-12f);
        float inv = 1.0f/d;
        vecn[(r*KNBR+t)*3+0] = vx*inv;
        vecn[(r*KNBR+t)*3+1] = vy*inv;
        vecn[(r*KNBR+t)*3+2] = vz*inv;
        const float PI = 3.14159265358979323846f;
        float cutv = (d <= 5.0f) ? 0.5f*(cosf(PI*d*0.2f) + 1.0f) : 0.0f;
        cutw[r*KNBR + t] = cutv;
        dist[t] = d; cutl[t] = cutv;
    }
    __syncthreads();

    for (int x = t; x < KNBR*NKER; x += 64) {
        int k = x / NKER, jj = x % NKER;
        float d = dist[k];
        float mu = 5.0f * (float)jj / 49.0f;
        float dd = d - mu;
        e_lds[k][jj] = __expf(-dd*dd*50.0f) * cutl[k];
    }
    __syncthreads();

    const int lx = t & 15, quad = t >> 4;
    #pragma unroll
    for (int grp = 0; grp < 4; ++grp) {
        const int ks = grp >> 1, part = grp & 1;
        short8 vv;
        #pragma unroll
        for (int j = 0; j < 8; ++j) {
            float v = e_lds[lx][ks*32 + quad*8 + j];
            unsigned b = __float_as_uint(v);
            if (part == 0) vv[j] = (short)(b >> 16);
            else {
                float rr = v - __uint_as_float(b & 0xFFFF0000u);
                vv[j] = (short)(__float_as_uint(rr) >> 16);
            }
        }
        *(short8*)(eA + (size_t)r*2048 + grp*512 + t*8) = vv;
    }
}

// ---------------------------------------------------------------------------
// Kernel 2: init s[rank] = emb[Z[perm[rank]]], o = 0, v0 = 0
// ---------------------------------------------------------------------------
__global__ __launch_bounds__(256) void init_kernel(
    const int* __restrict__ Z, const float* __restrict__ emb,
    const int* __restrict__ perm,
    float* __restrict__ s, float* __restrict__ o, float* __restrict__ v0)
{
    int stride = gridDim.x * blockDim.x;
    for (int idx = blockIdx.x*blockDim.x + threadIdx.x; idx < NATOMS*3*FDIM; idx += stride) {
        v0[idx] = 0.0f;
        if (idx < NATOMS*FDIM) {
            int a = idx >> 7, c = idx & 127;
            s[idx] = emb[Z[perm[a]]*FDIM + c];
            o[idx] = 0.0f;
        }
    }
}

// ---------------------------------------------------------------------------
// Kernel prep: wprep (blocks 0..383) + qprep (blocks 384..1343) merged
// ---------------------------------------------------------------------------
__global__ __launch_bounds__(64) void prep_kernel(
    const float* __restrict__ WeK, const float* __restrict__ WeV,
    const float* __restrict__ Wq, const float* __restrict__ Wk,
    const float* __restrict__ Wv,
    unsigned short* __restrict__ Wswz, unsigned short* __restrict__ Qswz)
{
    const int lane = threadIdx.x;
    if (blockIdx.x < NLAYER*32*2) {
        const int blk = blockIdx.x;
        const int ks = blk & 1;
        const int T  = (blk >> 1) & 31;
        const int l  = blk >> 6;
        const int quad = lane >> 4, x = lane & 15;
        unsigned short* dst = Wswz + (size_t)blk*1024 + lane*8;
        for (int j = 0; j < 8; ++j) {
            int k = ks*32 + quad*8 + j;
            float w = 0.0f;
            if (k < NKER)
                w = (T < 8) ? WeK[l*NKER*FDIM + k*FDIM + T*16 + x]
                            : WeV[(size_t)l*NKER*3*FDIM + k*3*FDIM + (T-8)*16 + x];
            unsigned b = __float_as_uint(w);
            dst[j] = (unsigned short)(b >> 16);
            float r = w - __uint_as_float(b & 0xFFFF0000u);
            dst[512 + j] = (unsigned short)(__float_as_uint(r) >> 16);
        }
    } else {
        const int blk = blockIdx.x - NLAYER*32*2;
        const int ks = blk & 3;
        const int ct = (blk >> 2) % 40;
        const int l  = blk / 160;
        const int quad = lane >> 4, lx = lane & 15;
        const int col = ct*16 + lx;
        unsigned short* dst = Qswz + (size_t)blk*1024 + lane*8;
        for (int j = 0; j < 8; ++j) {
            int k = ks*32 + quad*8 + j;
            float w;
            if (col < 128)      w = Wq[l*16384 + k*128 + col];
            else if (col < 256) w = Wk[l*16384 + k*128 + (col-128)];
            else                w = Wv[(size_t)l*49152 + k*384 + (col-256)];
            unsigned b = __float_as_uint(w);
            dst[j] = (unsigned short)(b >> 16);
            float r = w - __uint_as_float(b & 0xFFFF0000u);
            dst[512 + j] = (unsigned short)(__float_as_uint(r) >> 16);
        }
    }
}

// ---------------------------------------------------------------------------
// Kernel 3: QKV projection via MFMA bf16 hi/lo (rank-space rows)
// ---------------------------------------------------------------------------
__global__ __launch_bounds__(128) void proj_kernel(
    const float* __restrict__ S, const unsigned short* __restrict__ Qswz,
    float* __restrict__ QKV, int l)
{
    const int rt = blockIdx.x;
    const int t = threadIdx.x, wave = t >> 6, lane = t & 63;
    const int quad = lane >> 4, lx = lane & 15;
    const int cg = blockIdx.y*2 + wave;

    short8 ah[4], al[4];
    const float* srow = S + (size_t)(rt*16 + lx)*FDIM;
    #pragma unroll
    for (int ks = 0; ks < 4; ++ks) {
        float v[8];
        *(f32x4*)&v[0] = *(const f32x4*)(srow + ks*32 + quad*8);
        *(f32x4*)&v[4] = *(const f32x4*)(srow + ks*32 + quad*8 + 4);
        #pragma unroll
        for (int j = 0; j < 8; ++j) {
            unsigned b = __float_as_uint(v[j]);
            ah[ks][j] = (short)(b >> 16);
            float r = v[j] - __uint_as_float(b & 0xFFFF0000u);
            al[ks][j] = (short)(__float_as_uint(r) >> 16);
        }
    }
    for (int ci = 0; ci < 10; ++ci) {
        const int ct = cg*10 + ci;
        const unsigned short* wp = Qswz + (size_t)((l*40 + ct)*4)*1024 + lane*8;
        f32x4 acc = {0.0f, 0.0f, 0.0f, 0.0f};
        #pragma unroll
        for (int ks = 0; ks < 4; ++ks) {
            short8 bh = *(const short8*)(wp + ks*1024);
            short8 bl = *(const short8*)(wp + ks*1024 + 512);
            acc = __builtin_amdgcn_mfma_f32_16x16x32_bf16(ah[ks], bh, acc, 0, 0, 0);
            acc = __builtin_amdgcn_mfma_f32_16x16x32_bf16(ah[ks], bl, acc, 0, 0, 0);
            acc = __builtin_amdgcn_mfma_f32_16x16x32_bf16(al[ks], bh, acc, 0, 0, 0);
        }
        const int col = ct*16 + lx;
        #pragma unroll
        for (int r = 0; r < 4; ++r)
            QKV[(size_t)(rt*16 + quad*4 + r)*QKVW + col] = acc[r];
    }
}

// ---------------------------------------------------------------------------
// Kernel 4 (v7): 2 atoms/block. Logits computed IN phase A on key waves 0-1
// via in-wave shfl reduction (head spans 32 cols = 2 tiles x 16 lanes, all
// in-wave). Key waves write no fbuf; softmax is 4 threads/half; fbuf holds
// only the 384 value cols (stride 385).
// ---------------------------------------------------------------------------
__global__ __launch_bounds__(1024) void attn_kernel(
    const float* __restrict__ QKV, const int* __restrict__ idxs,
    const float* __restrict__ cutw, const float* __restrict__ vecn,
    const unsigned short* __restrict__ eA, const unsigned short* __restrict__ Wswz,
    const float* __restrict__ beK, const float* __restrict__ beV,
    float* __restrict__ s, float* __restrict__ o,
    const float* __restrict__ vin, float* __restrict__ vout, int l)
{
    __shared__ __align__(16) float fbuf[2][KNBR][FB];   // val cols 0..383
    __shared__ int   nidx[2][KNBR];
    __shared__ float cutv[2][KNBR];
    __shared__ float vnc[2][KNBR][3];
    __shared__ float lgs[2][KNBR][NHEAD];
    __shared__ float attns[2][KNBR][NHEAD];

    const int t = threadIdx.x;
    const int half = t >> 9, tl = t & 511;
    const int i = blockIdx.x*2 + half;
    const int wave = tl >> 6, lane = t & 63;
    const int quad = lane >> 4, lx = lane & 15;

    if (tl < KNBR) {
        nidx[half][tl] = idxs[i*KNBR + tl];
        cutv[half][tl] = cutw[i*KNBR + tl];
        vnc[half][tl][0] = vecn[(i*KNBR+tl)*3+0];
        vnc[half][tl][1] = vecn[(i*KNBR+tl)*3+1];
        vnc[half][tl][2] = vecn[(i*KNBR+tl)*3+2];
    }
    const unsigned short* ea = eA + (size_t)i*2048 + lane*8;
    short8 eh[2], el[2];
    eh[0] = *(const short8*)(ea + 0*512);
    el[0] = *(const short8*)(ea + 1*512);
    eh[1] = *(const short8*)(ea + 2*512);
    el[1] = *(const short8*)(ea + 3*512);
    __syncthreads();   // nidx ready

    // ---- phase A ----
    if (wave < 2) {
        // key path: filter cols 0..127, logits in-register
        float pk[4][2] = {};
        #pragma unroll
        for (int tt = 0; tt < 4; ++tt) {
            const int T = wave*4 + tt;
            const int col = T*16 + lx;
            const int hl = tt >> 1;
            f32x4 acc = {0.0f, 0.0f, 0.0f, 0.0f};
            #pragma unroll
            for (int ks = 0; ks < 2; ++ks) {
                const unsigned short* wp = Wswz + ((size_t)((l*32+T)*2+ks))*1024 + lane*8;
                short8 bh = *(const short8*)wp;
                short8 bl = *(const short8*)(wp + 512);
                acc = __builtin_amdgcn_mfma_f32_16x16x32_bf16(eh[ks], bh, acc, 0, 0, 0);
                acc = __builtin_amdgcn_mfma_f32_16x16x32_bf16(eh[ks], bl, acc, 0, 0, 0);
                acc = __builtin_amdgcn_mfma_f32_16x16x32_bf16(el[ks], bh, acc, 0, 0, 0);
            }
            const float b = beK[l*FDIM + col];
            const float q = QKV[(size_t)i*QKVW + col];
            #pragma unroll
            for (int r = 0; r < 4; ++r) {
                int k = quad*4 + r;
                if (k < KNBR) {
                    float f = silu_f(acc[r] + b);
                    float g = QKV[(size_t)nidx[half][k]*QKVW + FDIM + col];
                    pk[r][hl] += q * f * g;
                }
            }
        }
        #pragma unroll
        for (int off = 1; off < 16; off <<= 1) {
            #pragma unroll
            for (int r = 0; r < 4; ++r) {
                pk[r][0] += __shfl_xor(pk[r][0], off);
                pk[r][1] += __shfl_xor(pk[r][1], off);
            }
        }
        if (lx == 0) {
            #pragma unroll
            for (int r = 0; r < 4; ++r) {
                int k = quad*4 + r;
                if (k < KNBR) {
                    lgs[half][k][wave*2+0] = pk[r][0] * 0.125f;
                    lgs[half][k][wave*2+1] = pk[r][1] * 0.125f;
                }
            }
        }
    } else {
        // value path: filter cols 128..511 -> fbuf[.][col-128]
        #pragma unroll
        for (int tt = 0; tt < 4; ++tt) {
            const int T = wave*4 + tt;
            const int col = T*16 + lx;
            f32x4 acc = {0.0f, 0.0f, 0.0f, 0.0f};
            #pragma unroll
            for (int ks = 0; ks < 2; ++ks) {
                const unsigned short* wp = Wswz + ((size_t)((l*32+T)*2+ks))*1024 + lane*8;
                short8 bh = *(const short8*)wp;
                short8 bl = *(const short8*)(wp + 512);
                acc = __builtin_amdgcn_mfma_f32_16x16x32_bf16(eh[ks], bh, acc, 0, 0, 0);
                acc = __builtin_amdgcn_mfma_f32_16x16x32_bf16(eh[ks], bl, acc, 0, 0, 0);
                acc = __builtin_amdgcn_mfma_f32_16x16x32_bf16(el[ks], bh, acc, 0, 0, 0);
            }
            const float b = beV[(size_t)l*3*FDIM + (col - FDIM)];
            #pragma unroll
            for (int r = 0; r < 4; ++r) {
                int k = quad*4 + r;
                if (k < KNBR) {
                    float f = silu_f(acc[r] + b);
                    float g = QKV[(size_t)nidx[half][k]*QKVW + FDIM + col];
                    fbuf[half][k][col - FDIM] = f * g;
                }
            }
        }
    }
    __syncthreads();   // fbuf + lgs ready

    // ---- phase B: softmax (4 threads/half) + operand preload ----
    float pre[KNBR];
    if (tl < NHEAD) {
        const int h = tl;
        float m = -1e30f;
        #pragma unroll
        for (int k = 0; k < KNBR; ++k) m = fmaxf(m, lgs[half][k][h]);
        float ssum = 0.0f;
        float ex[KNBR];
        #pragma unroll
        for (int k = 0; k < KNBR; ++k) { ex[k] = __expf(lgs[half][k][h]-m); ssum += ex[k]; }
        float inv = 1.0f/ssum;
        #pragma unroll
        for (int k = 0; k < KNBR; ++k) attns[half][k][h] = ex[k]*inv*cutv[half][k];
    }
    if (tl < FDIM) {                       // m1 operands
        #pragma unroll
        for (int k = 0; k < KNBR; ++k) pre[k] = fbuf[half][k][tl];
    } else if (tl < 2*FDIM) {              // m2 operands
        const int cc = tl - FDIM;
        #pragma unroll
        for (int k = 0; k < KNBR; ++k) pre[k] = fbuf[half][k][FDIM + cc];
    } else {                               // m3 operands
        const int cc = (tl < 3*FDIM) ? (tl - 2*FDIM) : (tl - 3*FDIM);
        #pragma unroll
        for (int k = 0; k < KNBR; ++k) pre[k] = fbuf[half][k][2*FDIM + cc];
    }
    __syncthreads();   // attns published

    // ---- phase C ----
    float d3[3] = {0.0f, 0.0f, 0.0f};
    if (tl < FDIM) {
        const int c = tl, h = c >> 5;
        float ds = 0.0f;
        #pragma unroll
        for (int k = 0; k < KNBR; ++k) ds += attns[half][k][h]*pre[k];
        s[i*FDIM + c] += ds;
        o[i*FDIM + c] += ds;
    } else if (tl < 2*FDIM) {
        const int cc = tl - FDIM, h = cc >> 5;
        float d0 = 0.0f, d1 = 0.0f, d2 = 0.0f;
        #pragma unroll
        for (int k = 0; k < KNBR; ++k) {
            float w = attns[half][k][h]*pre[k];
            d0 += w*vnc[half][k][0]; d1 += w*vnc[half][k][1]; d2 += w*vnc[half][k][2];
        }
        fbuf[half][0][FDIM + cc] = d0;     // dv partials into consumed m2 region
        fbuf[half][1][FDIM + cc] = d1;
        fbuf[half][2][FDIM + cc] = d2;
    } else if (tl < 3*FDIM) {
        const int cc = tl - 2*FDIM, h = cc >> 5;
        #pragma unroll
        for (int k = 0; k < 8; ++k) {
            float w = attns[half][k][h]*pre[k];
            const float* vb = vin + (size_t)nidx[half][k]*3*FDIM + cc;
            d3[0] += w*vb[0*FDIM]; d3[1] += w*vb[1*FDIM]; d3[2] += w*vb[2*FDIM];
        }
    } else {
        const int cc = tl - 3*FDIM, h = cc >> 5;
        float e0 = 0.0f, e1 = 0.0f, e2 = 0.0f;
        #pragma unroll
        for (int k = 8; k < KNBR; ++k) {
            float w = attns[half][k][h]*pre[k];
            const float* vb = vin + (size_t)nidx[half][k]*3*FDIM + cc;
            e0 += w*vb[0*FDIM]; e1 += w*vb[1*FDIM]; e2 += w*vb[2*FDIM];
        }
        fbuf[half][3][FDIM + cc] = e0;
        fbuf[half][4][FDIM + cc] = e1;
        fbuf[half][5][FDIM + cc] = e2;
    }
    __syncthreads();   // dv partials ready

    // ---- phase D ----
    if (tl >= 2*FDIM && tl < 3*FDIM) {
        const int cc = tl - 2*FDIM;
        #pragma unroll
        for (int x = 0; x < 3; ++x) {
            size_t off = (size_t)i*3*FDIM + x*FDIM + cc;
            vout[off] = vin[off] + fbuf[half][x][FDIM + cc]
                                 + fbuf[half][3+x][FDIM + cc] + d3[x];
        }
    }
}

// ---------------------------------------------------------------------------
// Kernel 5: LayerNorm + readout -> per-atom scalar (rank space)
// ---------------------------------------------------------------------------
__global__ __launch_bounds__(128) void final_kernel(
    const float* __restrict__ o, const float* __restrict__ lng, const float* __restrict__ lnb,
    const float* __restrict__ Wo1, const float* __restrict__ Wo2,
    const float* __restrict__ batch, const int* __restrict__ perm,
    float* __restrict__ hout)
{
    __shared__ float red[128];
    __shared__ float on[128];
    const int i = blockIdx.x, t = threadIdx.x;
    float x = o[i*FDIM + t];
    red[t] = x; __syncthreads();
    for (int off = 64; off > 0; off >>= 1) { if (t < off) red[t] += red[t+off]; __syncthreads(); }
    float mean = red[0] * (1.0f/128.0f);
    __syncthreads();
    float xm = x - mean;
    red[t] = xm*xm; __syncthreads();
    for (int off = 64; off > 0; off >>= 1) { if (t < off) red[t] += red[t+off]; __syncthreads(); }
    float var = red[0] * (1.0f/128.0f);
    __syncthreads();
    on[t] = xm * rsqrtf(var + 1e-5f) * lng[t] + lnb[t];
    __syncthreads();
    float acc = 0.0f;
    #pragma unroll 8
    for (int j = 0; j < 128; ++j) acc += on[j] * Wo1[j*128 + t];
    float h = silu_f(acc) * Wo2[t];
    red[t] = h; __syncthreads();
    for (int off = 64; off > 0; off >>= 1) { if (t < off) red[t] += red[t+off]; __syncthreads(); }
    if (t == 0) hout[i] = red[0] * batch[perm[i]];
}

// ---------------------------------------------------------------------------
// Kernel 6: single-block tree reduction of hout[4096] -> out[0]
// ---------------------------------------------------------------------------
__global__ __launch_bounds__(1024) void reduce_kernel(
    const float* __restrict__ hout, float* __restrict__ out)
{
    __shared__ float red[1024];
    const int t = threadIdx.x;
    float a = hout[t] + hout[t+1024] + hout[t+2048] + hout[t+3072];
    red[t] = a; __syncthreads();
    for (int off = 512; off > 0; off >>= 1) {
        if (t < off) red[t] += red[t+off];
        __syncthreads();
    }
    if (t == 0) out[0] = red[0];
}

// ---------------------------------------------------------------------------
extern "C" void kernel_launch(void* const* d_in, const int* in_sizes, int n_in,
                              void* d_out, int out_size, void* d_ws, size_t ws_size,
                              hipStream_t stream)
{
    const int*   Z     = (const int*)  d_in[0];
    const float* R     = (const float*)d_in[1];
    const float* batch = (const float*)d_in[2];
    const float* emb   = (const float*)d_in[3];
    const float* Wq    = (const float*)d_in[4];
    const float* Wk    = (const float*)d_in[5];
    const float* Wv    = (const float*)d_in[6];
    const float* WeK   = (const float*)d_in[7];
    const float* beK   = (const float*)d_in[8];
    const float* WeV   = (const float*)d_in[9];
    const float* beV   = (const float*)d_in[10];
    const float* lng   = (const float*)d_in[11];
    const float* lnb   = (const float*)d_in[12];
    const float* Wo1   = (const float*)d_in[13];
    const float* Wo2   = (const float*)d_in[14];
    float* out = (float*)d_out;

    float* fws = (float*)d_ws;
    float* s    = fws; fws += NATOMS*FDIM;
    float* o    = fws; fws += NATOMS*FDIM;
    float* v0   = fws; fws += NATOMS*3*FDIM;
    float* v1   = fws; fws += NATOMS*3*FDIM;
    float* qkv  = fws; fws += NATOMS*QKVW;
    float* cutw = fws; fws += NATOMS*KNBR;
    float* vecn = fws; fws += NATOMS*KNBR*3;
    float* hout = fws; fws += NATOMS;
    float* Rs   = fws; fws += NATOMS*3;
    float* bsrt = fws; fws += NATOMS;
    int*   idxs = (int*)fws; fws += NATOMS*KNBR;
    int*   perm = (int*)fws; fws += NATOMS;
    int*   cells= (int*)fws; fws += 4097;
    fws += 3;   // realign
    unsigned short* eA   = (unsigned short*)fws;            // 16 MB
    fws += (NATOMS*2048) / 2;
    unsigned short* Wswz = (unsigned short*)fws;            // 768 KB
    fws += (NLAYER*32*2*1024) / 2;
    unsigned short* Qswz = (unsigned short*)fws;            // 1.92 MB

    morton_kernel<<<1, 1024, 0, stream>>>(R, batch, perm, Rs, bsrt, cells);
    prep_kernel<<<NLAYER*32*2 + NLAYER*40*4, 64, 0, stream>>>(WeK, WeV, Wq, Wk, Wv, Wswz, Qswz);
    knn_kernel<<<NATOMS, 64, 0, stream>>>(Rs, bsrt, cells, idxs, cutw, vecn, eA);
    init_kernel<<<1024, 256, 0, stream>>>(Z, emb, perm, s, o, v0);
    for (int l = 0; l < NLAYER; ++l) {
        proj_kernel<<<dim3(256, 2), 128, 0, stream>>>(s, Qswz, qkv, l);
        float* vin  = (l & 1) ? v1 : v0;
        float* vout = (l & 1) ? v0 : v1;
        attn_kernel<<<NATOMS/2, 1024, 0, stream>>>(qkv, idxs, cutw, vecn, eA, Wswz,
                                                   beK, beV, s, o, vin, vout, l);
    }
    final_kernel<<<NATOMS, 128, 0, stream>>>(o, lng, lnb, Wo1, Wo2, batch, perm, hout);
    reduce_kernel<<<1, 1024, 0, stream>>>(hout, out);
}

// Round 10
// 499.107 us; speedup vs baseline: 1.2119x; 1.2119x over previous
//
#include <hip/hip_runtime.h>
#include <math.h>

#define NATOMS  4096
#define FDIM    128
#define NHEAD   4
#define DHEAD   32
#define KNBR    15
#define NKER    50
#define NLAYER  6
#define QKVW    640   // 128 q + 128 k + 384 v
#define LISTCAP 768

typedef __attribute__((ext_vector_type(8))) short short8;
typedef __attribute__((ext_vector_type(4))) float f32x4;

__device__ __forceinline__ float silu_f(float x) { return x / (1.0f + __expf(-x)); }

__device__ __forceinline__ unsigned long long shfl_xor_u64(unsigned long long v, int m) {
    unsigned lo = (unsigned)v, hi = (unsigned)(v >> 32);
    lo = (unsigned)__shfl_xor((int)lo, m);
    hi = (unsigned)__shfl_xor((int)hi, m);
    return ((unsigned long long)hi << 32) | lo;
}
__device__ __forceinline__ unsigned long long min_u64(unsigned long long a, unsigned long long b) {
    return a < b ? a : b;
}
__device__ __forceinline__ int spread3(int v) {   // 4 bits -> bits 0,3,6,9
    return (v & 1) | ((v & 2) << 2) | ((v & 4) << 4) | ((v & 8) << 6);
}

// ---------------------------------------------------------------------------
// Kernel 0: Morton counting-sort -> perm, sorted coords/batch, cell CSR
// ---------------------------------------------------------------------------
__global__ __launch_bounds__(1024) void morton_kernel(
    const float* __restrict__ R, const float* __restrict__ batch,
    int* __restrict__ perm, float* __restrict__ Rs,
    float* __restrict__ batch_s, int* __restrict__ cell_start)
{
    __shared__ int hist[4096];
    __shared__ int tscan[1024];
    const int t = threadIdx.x;
    int codes[4];
    float xs[4], ys[4], zs[4];
    #pragma unroll
    for (int u = 0; u < 4; ++u) hist[t*4 + u] = 0;
    __syncthreads();
    #pragma unroll
    for (int u = 0; u < 4; ++u) {
        int i = t + u*1024;
        float x = R[i*3+0], y = R[i*3+1], z = R[i*3+2];
        xs[u] = x; ys[u] = y; zs[u] = z;
        int cx = min(15, max(0, (int)(x * 0.4f)));
        int cy = min(15, max(0, (int)(y * 0.4f)));
        int cz = min(15, max(0, (int)(z * 0.4f)));
        int code = spread3(cx) | (spread3(cy) << 1) | (spread3(cz) << 2);
        codes[u] = code;
        atomicAdd(&hist[code], 1);
    }
    __syncthreads();
    int loc[4], s0 = 0;
    #pragma unroll
    for (int u = 0; u < 4; ++u) { loc[u] = hist[t*4 + u]; s0 += loc[u]; }
    tscan[t] = s0;
    __syncthreads();
    for (int off = 1; off < 1024; off <<= 1) {
        int v = tscan[t];
        int a = (t >= off) ? tscan[t - off] : 0;
        __syncthreads();
        tscan[t] = v + a;
        __syncthreads();
    }
    int run = tscan[t] - s0;
    #pragma unroll
    for (int u = 0; u < 4; ++u) {
        hist[t*4 + u] = run;
        cell_start[t*4 + u] = run;
        run += loc[u];
    }
    if (t == 0) cell_start[4096] = NATOMS;
    __syncthreads();
    #pragma unroll
    for (int u = 0; u < 4; ++u) {
        int i = t + u*1024;
        int r = atomicAdd(&hist[codes[u]], 1);
        perm[r] = i;
        Rs[r*3+0] = xs[u]; Rs[r*3+1] = ys[u]; Rs[r*3+2] = zs[u];
        batch_s[r] = batch[i];
    }
}

// ---------------------------------------------------------------------------
// Kernel 1: cell-list KNN, one wave per atom; bakes eA (bf16 hi/lo A-frags)
// ---------------------------------------------------------------------------
__global__ __launch_bounds__(64) void knn_kernel(
    const float* __restrict__ Rs, const float* __restrict__ batch_s,
    const int* __restrict__ cell_start,
    int* __restrict__ idxs, float* __restrict__ cutw,
    float* __restrict__ vecn, unsigned short* __restrict__ eA)
{
    __shared__ unsigned long long list[LISTCAP];
    __shared__ int   ridx[LISTCAP];
    __shared__ float e_lds[16][68];
    __shared__ float dist[KNBR];
    __shared__ float cutl[KNBR];
    __shared__ int   selr[KNBR];
    __shared__ int   cnt;
    const int r = blockIdx.x, t = threadIdx.x;
    if (t == 0) cnt = 0;
    for (int x = t; x < 16*68; x += 64) ((float*)e_lds)[x] = 0.0f;
    const float xi = Rs[r*3+0], yi = Rs[r*3+1], zi = Rs[r*3+2];
    const float bi = batch_s[r];
    const float sqi = xi*xi + yi*yi + zi*zi;
    const int cx = min(15, max(0, (int)(xi * 0.4f)));
    const int cy = min(15, max(0, (int)(yi * 0.4f)));
    const int cz = min(15, max(0, (int)(zi * 0.4f)));
    __syncthreads();

    for (int cid = t; cid < 343; cid += 64) {
        int nx = cx + (cid % 7) - 3;
        int ny = cy + ((cid / 7) % 7) - 3;
        int nz = cz + (cid / 49) - 3;
        if (nx < 0 || nx > 15 || ny < 0 || ny > 15 || nz < 0 || nz > 15) continue;
        int code = spread3(nx) | (spread3(ny) << 1) | (spread3(nz) << 2);
        int s0 = cell_start[code], s1 = cell_start[code + 1];
        for (int r2 = s0; r2 < s1; ++r2) {
            if (r2 == r) continue;
            float xj = Rs[r2*3+0], yj = Rs[r2*3+1], zj = Rs[r2*3+2];
            if (bi * batch_s[r2] == 0.0f) continue;
            float sqj = xj*xj + yj*yj + zj*zj;
            float d2 = sqi + sqj - 2.0f*(xi*xj + yi*yj + zi*zj);
            d2 = fmaxf(d2, 0.0f);
            int slot = atomicAdd(&cnt, 1);
            if (slot < LISTCAP) {
                list[slot] = ((unsigned long long)__float_as_uint(d2) << 32) | (unsigned)slot;
                ridx[slot] = r2;
            }
        }
    }
    __syncthreads();
    const int n = min(cnt, LISTCAP);

    unsigned long long cand = ~0ull;
    for (int idx = t; idx < n; idx += 64) cand = min_u64(cand, list[idx]);
    for (int k = 0; k < KNBR; ++k) {
        unsigned long long w = cand;
        #pragma unroll
        for (int off = 1; off < 64; off <<= 1)
            w = min_u64(w, shfl_xor_u64(w, off));
        int slot = (int)(unsigned)w;
        if (t == 0) selr[k] = ridx[slot];
        if ((slot & 63) == t) {
            list[slot] = ~0ull;
            cand = ~0ull;
            for (int idx = t; idx < n; idx += 64) cand = min_u64(cand, list[idx]);
        }
        __syncthreads();
    }

    if (t < KNBR) {
        int r2 = selr[t];
        idxs[r*KNBR + t] = r2;
        float vx = Rs[r2*3+0]-xi, vy = Rs[r2*3+1]-yi, vz = Rs[r2*3+2]-zi;
        float d = sqrtf(vx*vx + vy*vy + vz*vz + 1e-12f);
        float inv = 1.0f/d;
        vecn[(r*KNBR+t)*3+0] = vx*inv;
        vecn[(r*KNBR+t)*3+1] = vy*inv;
        vecn[(r*KNBR+t)*3+2] = vz*inv;
        const float PI = 3.14159265358979323846f;
        float cutv = (d <= 5.0f) ? 0.5f*(cosf(PI*d*0.2f) + 1.0f) : 0.0f;
        cutw[r*KNBR + t] = cutv;
        dist[t] = d; cutl[t] = cutv;
    }
    __syncthreads();

    for (int x = t; x < KNBR*NKER; x += 64) {
        int k = x / NKER, jj = x % NKER;
        float d = dist[k];
        float mu = 5.0f * (float)jj / 49.0f;
        float dd = d - mu;
        e_lds[k][jj] = __expf(-dd*dd*50.0f) * cutl[k];
    }
    __syncthreads();

    const int lx = t & 15, quad = t >> 4;
    #pragma unroll
    for (int grp = 0; grp < 4; ++grp) {
        const int ks = grp >> 1, part = grp & 1;
        short8 vv;
        #pragma unroll
        for (int j = 0; j < 8; ++j) {
            float v = e_lds[lx][ks*32 + quad*8 + j];
            unsigned b = __float_as_uint(v);
            if (part == 0) vv[j] = (short)(b >> 16);
            else {
                float rr = v - __uint_as_float(b & 0xFFFF0000u);
                vv[j] = (short)(__float_as_uint(rr) >> 16);
            }
        }
        *(short8*)(eA + (size_t)r*2048 + grp*512 + t*8) = vv;
    }
}

// ---------------------------------------------------------------------------
// Kernel 2: init s[rank] = emb[Z[perm[rank]]], o = 0, v0 = 0
// ---------------------------------------------------------------------------
__global__ __launch_bounds__(256) void init_kernel(
    const int* __restrict__ Z, const float* __restrict__ emb,
    const int* __restrict__ perm,
    float* __restrict__ s, float* __restrict__ o, float* __restrict__ v0)
{
    int stride = gridDim.x * blockDim.x;
    for (int idx = blockIdx.x*blockDim.x + threadIdx.x; idx < NATOMS*3*FDIM; idx += stride) {
        v0[idx] = 0.0f;
        if (idx < NATOMS*FDIM) {
            int a = idx >> 7, c = idx & 127;
            s[idx] = emb[Z[perm[a]]*FDIM + c];
            o[idx] = 0.0f;
        }
    }
}

// ---------------------------------------------------------------------------
// Kernel prep: wprep (blocks 0..383) + qprep (blocks 384..1343) merged
// ---------------------------------------------------------------------------
__global__ __launch_bounds__(64) void prep_kernel(
    const float* __restrict__ WeK, const float* __restrict__ WeV,
    const float* __restrict__ Wq, const float* __restrict__ Wk,
    const float* __restrict__ Wv,
    unsigned short* __restrict__ Wswz, unsigned short* __restrict__ Qswz)
{
    const int lane = threadIdx.x;
    if (blockIdx.x < NLAYER*32*2) {
        const int blk = blockIdx.x;
        const int ks = blk & 1;
        const int T  = (blk >> 1) & 31;
        const int l  = blk >> 6;
        const int quad = lane >> 4, x = lane & 15;
        unsigned short* dst = Wswz + (size_t)blk*1024 + lane*8;
        for (int j = 0; j < 8; ++j) {
            int k = ks*32 + quad*8 + j;
            float w = 0.0f;
            if (k < NKER)
                w = (T < 8) ? WeK[l*NKER*FDIM + k*FDIM + T*16 + x]
                            : WeV[(size_t)l*NKER*3*FDIM + k*3*FDIM + (T-8)*16 + x];
            unsigned b = __float_as_uint(w);
            dst[j] = (unsigned short)(b >> 16);
            float r = w - __uint_as_float(b & 0xFFFF0000u);
            dst[512 + j] = (unsigned short)(__float_as_uint(r) >> 16);
        }
    } else {
        const int blk = blockIdx.x - NLAYER*32*2;
        const int ks = blk & 3;
        const int ct = (blk >> 2) % 40;
        const int l  = blk / 160;
        const int quad = lane >> 4, lx = lane & 15;
        const int col = ct*16 + lx;
        unsigned short* dst = Qswz + (size_t)blk*1024 + lane*8;
        for (int j = 0; j < 8; ++j) {
            int k = ks*32 + quad*8 + j;
            float w;
            if (col < 128)      w = Wq[l*16384 + k*128 + col];
            else if (col < 256) w = Wk[l*16384 + k*128 + (col-128)];
            else                w = Wv[(size_t)l*49152 + k*384 + (col-256)];
            unsigned b = __float_as_uint(w);
            dst[j] = (unsigned short)(b >> 16);
            float r = w - __uint_as_float(b & 0xFFFF0000u);
            dst[512 + j] = (unsigned short)(__float_as_uint(r) >> 16);
        }
    }
}

// ---------------------------------------------------------------------------
// Kernel 3: QKV projection via MFMA bf16 hi/lo (rank-space rows)
// grid (256, 4) x 128 thr -> 2048 waves (8/CU); each wave: 5 col-tiles.
// (R9 had 4 waves/CU -> latency-bound; doubling grid.y fixed occupancy.)
// ---------------------------------------------------------------------------
__global__ __launch_bounds__(128) void proj_kernel(
    const float* __restrict__ S, const unsigned short* __restrict__ Qswz,
    float* __restrict__ QKV, int l)
{
    const int rt = blockIdx.x;
    const int t = threadIdx.x, wave = t >> 6, lane = t & 63;
    const int quad = lane >> 4, lx = lane & 15;
    const int cg = blockIdx.y*2 + wave;     // 0..7, each covers 5 col-tiles

    short8 ah[4], al[4];
    const float* srow = S + (size_t)(rt*16 + lx)*FDIM;
    #pragma unroll
    for (int ks = 0; ks < 4; ++ks) {
        float v[8];
        *(f32x4*)&v[0] = *(const f32x4*)(srow + ks*32 + quad*8);
        *(f32x4*)&v[4] = *(const f32x4*)(srow + ks*32 + quad*8 + 4);
        #pragma unroll
        for (int j = 0; j < 8; ++j) {
            unsigned b = __float_as_uint(v[j]);
            ah[ks][j] = (short)(b >> 16);
            float r = v[j] - __uint_as_float(b & 0xFFFF0000u);
            al[ks][j] = (short)(__float_as_uint(r) >> 16);
        }
    }
    for (int ci = 0; ci < 5; ++ci) {
        const int ct = cg*5 + ci;
        const unsigned short* wp = Qswz + (size_t)((l*40 + ct)*4)*1024 + lane*8;
        f32x4 acc = {0.0f, 0.0f, 0.0f, 0.0f};
        #pragma unroll
        for (int ks = 0; ks < 4; ++ks) {
            short8 bh = *(const short8*)(wp + ks*1024);
            short8 bl = *(const short8*)(wp + ks*1024 + 512);
            acc = __builtin_amdgcn_mfma_f32_16x16x32_bf16(ah[ks], bh, acc, 0, 0, 0);
            acc = __builtin_amdgcn_mfma_f32_16x16x32_bf16(ah[ks], bl, acc, 0, 0, 0);
            acc = __builtin_amdgcn_mfma_f32_16x16x32_bf16(al[ks], bh, acc, 0, 0, 0);
        }
        const int col = ct*16 + lx;
        #pragma unroll
        for (int r = 0; r < 4; ++r)
            QKV[(size_t)(rt*16 + quad*4 + r)*QKVW + col] = acc[r];
    }
}

// ---------------------------------------------------------------------------
// Kernel 4 (R8 version): 2 atoms per block (1024 thr, 16 waves).
// dv partials live in fbuf's consumed m2 column region (LDS < 64 KB).
// ---------------------------------------------------------------------------
__global__ __launch_bounds__(1024) void attn_kernel(
    const float* __restrict__ QKV, const int* __restrict__ idxs,
    const float* __restrict__ cutw, const float* __restrict__ vecn,
    const unsigned short* __restrict__ eA, const unsigned short* __restrict__ Wswz,
    const float* __restrict__ beK, const float* __restrict__ beV,
    float* __restrict__ s, float* __restrict__ o,
    const float* __restrict__ vin, float* __restrict__ vout, int l)
{
    __shared__ __align__(16) float fbuf[2][KNBR][513];
    __shared__ int   nidx[2][KNBR];
    __shared__ float cutv[2][KNBR];
    __shared__ float vnc[2][KNBR][3];
    __shared__ float attns[2][KNBR][NHEAD];

    const int t = threadIdx.x;
    const int half = t >> 9, tl = t & 511;
    const int i = blockIdx.x*2 + half;
    const int wave = tl >> 6, lane = t & 63;
    const int quad = lane >> 4, lx = lane & 15;

    if (tl < KNBR) {
        nidx[half][tl] = idxs[i*KNBR + tl];
        cutv[half][tl] = cutw[i*KNBR + tl];
        vnc[half][tl][0] = vecn[(i*KNBR+tl)*3+0];
        vnc[half][tl][1] = vecn[(i*KNBR+tl)*3+1];
        vnc[half][tl][2] = vecn[(i*KNBR+tl)*3+2];
    }
    const unsigned short* ea = eA + (size_t)i*2048 + lane*8;
    short8 eh[2], el[2];
    eh[0] = *(const short8*)(ea + 0*512);
    el[0] = *(const short8*)(ea + 1*512);
    eh[1] = *(const short8*)(ea + 2*512);
    el[1] = *(const short8*)(ea + 3*512);
    __syncthreads();   // nidx ready

    // ---- phase A: MFMA filter + epilogue gather ----
    #pragma unroll
    for (int tt = 0; tt < 4; ++tt) {
        const int T = wave*4 + tt;
        const int col = T*16 + lx;
        f32x4 acc = {0.0f, 0.0f, 0.0f, 0.0f};
        #pragma unroll
        for (int ks = 0; ks < 2; ++ks) {
            const unsigned short* wp = Wswz + ((size_t)((l*32+T)*2+ks))*1024 + lane*8;
            short8 bh = *(const short8*)wp;
            short8 bl = *(const short8*)(wp + 512);
            acc = __builtin_amdgcn_mfma_f32_16x16x32_bf16(eh[ks], bh, acc, 0, 0, 0);
            acc = __builtin_amdgcn_mfma_f32_16x16x32_bf16(eh[ks], bl, acc, 0, 0, 0);
            acc = __builtin_amdgcn_mfma_f32_16x16x32_bf16(el[ks], bh, acc, 0, 0, 0);
        }
        const float b = (col < FDIM) ? beK[l*FDIM + col]
                                     : beV[(size_t)l*3*FDIM + (col - FDIM)];
        const int goff = (col < FDIM) ? (FDIM + col) : (2*FDIM + (col - FDIM));
        #pragma unroll
        for (int r = 0; r < 4; ++r) {
            int k = quad*4 + r;
            if (k < KNBR) {
                float f = silu_f(acc[r] + b);
                float g = QKV[(size_t)nidx[half][k]*QKVW + goff];
                fbuf[half][k][col] = f * g;
            }
        }
    }
    __syncthreads();   // fbuf filtered

    // ---- phase B: logits+softmax (tl<128); others preload phase-C operands ----
    float pre[KNBR];
    if (tl < FDIM) {
        const int c = tl, h = c >> 5;
        const float q = QKV[(size_t)i*QKVW + c];
        float lg[KNBR];
        #pragma unroll
        for (int k = 0; k < KNBR; ++k) {
            float p = q * fbuf[half][k][c];
            p += __shfl_xor(p, 1);
            p += __shfl_xor(p, 2);
            p += __shfl_xor(p, 4);
            p += __shfl_xor(p, 8);
            p += __shfl_xor(p, 16);
            lg[k] = p * 0.125f;
        }
        float m = -1e30f;
        #pragma unroll
        for (int k = 0; k < KNBR; ++k) m = fmaxf(m, lg[k]);
        float ssum = 0.0f;
        #pragma unroll
        for (int k = 0; k < KNBR; ++k) { lg[k] = __expf(lg[k]-m); ssum += lg[k]; }
        float inv = 1.0f/ssum;
        if ((c & 31) == 0) {
            #pragma unroll
            for (int k = 0; k < KNBR; ++k) attns[half][k][h] = lg[k]*inv*cutv[half][k];
        }
    } else if (tl < 2*FDIM) {
        const int cc = tl - FDIM;
        #pragma unroll
        for (int k = 0; k < KNBR; ++k) pre[k] = fbuf[half][k][2*FDIM + cc];   // m2
    } else {
        const int cc = (tl < 3*FDIM) ? (tl - 2*FDIM) : (tl - 3*FDIM);
        #pragma unroll
        for (int k = 0; k < KNBR; ++k) pre[k] = fbuf[half][k][3*FDIM + cc];   // m3
    }
    __syncthreads();   // attns published

    // ---- phase C ----
    float d3[3] = {0.0f, 0.0f, 0.0f};
    if (tl < FDIM) {
        const int c = tl, h = c >> 5;
        float ds = 0.0f;
        #pragma unroll
        for (int k = 0; k < KNBR; ++k) ds += attns[half][k][h]*fbuf[half][k][FDIM + c];
        s[i*FDIM + c] += ds;
        o[i*FDIM + c] += ds;
    } else if (tl < 2*FDIM) {
        const int cc = tl - FDIM, h = cc >> 5;
        float d0 = 0.0f, d1 = 0.0f, d2 = 0.0f;
        #pragma unroll
        for (int k = 0; k < KNBR; ++k) {
            float w = attns[half][k][h]*pre[k];
            d0 += w*vnc[half][k][0]; d1 += w*vnc[half][k][1]; d2 += w*vnc[half][k][2];
        }
        fbuf[half][0][2*FDIM + cc] = d0;      // dv partials into consumed m2 region
        fbuf[half][1][2*FDIM + cc] = d1;
        fbuf[half][2][2*FDIM + cc] = d2;
    } else if (tl < 3*FDIM) {
        const int cc = tl - 2*FDIM, h = cc >> 5;
        #pragma unroll
        for (int k = 0; k < 8; ++k) {
            float w = attns[half][k][h]*pre[k];
            const float* vb = vin + (size_t)nidx[half][k]*3*FDIM + cc;
            d3[0] += w*vb[0*FDIM]; d3[1] += w*vb[1*FDIM]; d3[2] += w*vb[2*FDIM];
        }
    } else {
        const int cc = tl - 3*FDIM, h = cc >> 5;
        float e0 = 0.0f, e1 = 0.0f, e2 = 0.0f;
        #pragma unroll
        for (int k = 8; k < KNBR; ++k) {
            float w = attns[half][k][h]*pre[k];
            const float* vb = vin + (size_t)nidx[half][k]*3*FDIM + cc;
            e0 += w*vb[0*FDIM]; e1 += w*vb[1*FDIM]; e2 += w*vb[2*FDIM];
        }
        fbuf[half][3][2*FDIM + cc] = e0;
        fbuf[half][4][2*FDIM + cc] = e1;
        fbuf[half][5][2*FDIM + cc] = e2;
    }
    __syncthreads();   // dv partials ready

    // ---- phase D ----
    if (tl >= 2*FDIM && tl < 3*FDIM) {
        const int cc = tl - 2*FDIM;
        #pragma unroll
        for (int x = 0; x < 3; ++x) {
            size_t off = (size_t)i*3*FDIM + x*FDIM + cc;
            vout[off] = vin[off] + fbuf[half][x][2*FDIM + cc]
                                 + fbuf[half][3+x][2*FDIM + cc] + d3[x];
        }
    }
}

// ---------------------------------------------------------------------------
// Kernel 5: LayerNorm + readout -> per-atom scalar (rank space)
// ---------------------------------------------------------------------------
__global__ __launch_bounds__(128) void final_kernel(
    const float* __restrict__ o, const float* __restrict__ lng, const float* __restrict__ lnb,
    const float* __restrict__ Wo1, const float* __restrict__ Wo2,
    const float* __restrict__ batch, const int* __restrict__ perm,
    float* __restrict__ hout)
{
    __shared__ float red[128];
    __shared__ float on[128];
    const int i = blockIdx.x, t = threadIdx.x;
    float x = o[i*FDIM + t];
    red[t] = x; __syncthreads();
    for (int off = 64; off > 0; off >>= 1) { if (t < off) red[t] += red[t+off]; __syncthreads(); }
    float mean = red[0] * (1.0f/128.0f);
    __syncthreads();
    float xm = x - mean;
    red[t] = xm*xm; __syncthreads();
    for (int off = 64; off > 0; off >>= 1) { if (t < off) red[t] += red[t+off]; __syncthreads(); }
    float var = red[0] * (1.0f/128.0f);
    __syncthreads();
    on[t] = xm * rsqrtf(var + 1e-5f) * lng[t] + lnb[t];
    __syncthreads();
    float acc = 0.0f;
    #pragma unroll 8
    for (int j = 0; j < 128; ++j) acc += on[j] * Wo1[j*128 + t];
    float h = silu_f(acc) * Wo2[t];
    red[t] = h; __syncthreads();
    for (int off = 64; off > 0; off >>= 1) { if (t < off) red[t] += red[t+off]; __syncthreads(); }
    if (t == 0) hout[i] = red[0] * batch[perm[i]];
}

// ---------------------------------------------------------------------------
// Kernel 6: single-block tree reduction of hout[4096] -> out[0]
// ---------------------------------------------------------------------------
__global__ __launch_bounds__(1024) void reduce_kernel(
    const float* __restrict__ hout, float* __restrict__ out)
{
    __shared__ float red[1024];
    const int t = threadIdx.x;
    float a = hout[t] + hout[t+1024] + hout[t+2048] + hout[t+3072];
    red[t] = a; __syncthreads();
    for (int off = 512; off > 0; off >>= 1) {
        if (t < off) red[t] += red[t+off];
        __syncthreads();
    }
    if (t == 0) out[0] = red[0];
}

// ---------------------------------------------------------------------------
extern "C" void kernel_launch(void* const* d_in, const int* in_sizes, int n_in,
                              void* d_out, int out_size, void* d_ws, size_t ws_size,
                              hipStream_t stream)
{
    const int*   Z     = (const int*)  d_in[0];
    const float* R     = (const float*)d_in[1];
    const float* batch = (const float*)d_in[2];
    const float* emb   = (const float*)d_in[3];
    const float* Wq    = (const float*)d_in[4];
    const float* Wk    = (const float*)d_in[5];
    const float* Wv    = (const float*)d_in[6];
    const float* WeK   = (const float*)d_in[7];
    const float* beK   = (const float*)d_in[8];
    const float* WeV   = (const float*)d_in[9];
    const float* beV   = (const float*)d_in[10];
    const float* lng   = (const float*)d_in[11];
    const float* lnb   = (const float*)d_in[12];
    const float* Wo1   = (const float*)d_in[13];
    const float* Wo2   = (const float*)d_in[14];
    float* out = (float*)d_out;

    float* fws = (float*)d_ws;
    float* s    = fws; fws += NATOMS*FDIM;
    float* o    = fws; fws += NATOMS*FDIM;
    float* v0   = fws; fws += NATOMS*3*FDIM;
    float* v1   = fws; fws += NATOMS*3*FDIM;
    float* qkv  = fws; fws += NATOMS*QKVW;
    float* cutw = fws; fws += NATOMS*KNBR;
    float* vecn = fws; fws += NATOMS*KNBR*3;
    float* hout = fws; fws += NATOMS;
    float* Rs   = fws; fws += NATOMS*3;
    float* bsrt = fws; fws += NATOMS;
    int*   idxs = (int*)fws; fws += NATOMS*KNBR;
    int*   perm = (int*)fws; fws += NATOMS;
    int*   cells= (int*)fws; fws += 4097;
    fws += 3;   // realign
    unsigned short* eA   = (unsigned short*)fws;            // 16 MB
    fws += (NATOMS*2048) / 2;
    unsigned short* Wswz = (unsigned short*)fws;            // 768 KB
    fws += (NLAYER*32*2*1024) / 2;
    unsigned short* Qswz = (unsigned short*)fws;            // 1.92 MB

    morton_kernel<<<1, 1024, 0, stream>>>(R, batch, perm, Rs, bsrt, cells);
    prep_kernel<<<NLAYER*32*2 + NLAYER*40*4, 64, 0, stream>>>(WeK, WeV, Wq, Wk, Wv, Wswz, Qswz);
    knn_kernel<<<NATOMS, 64, 0, stream>>>(Rs, bsrt, cells, idxs, cutw, vecn, eA);
    init_kernel<<<1024, 256, 0, stream>>>(Z, emb, perm, s, o, v0);
    for (int l = 0; l < NLAYER; ++l) {
        proj_kernel<<<dim3(256, 4), 128, 0, stream>>>(s, Qswz, qkv, l);
        float* vin  = (l & 1) ? v1 : v0;
        float* vout = (l & 1) ? v0 : v1;
        attn_kernel<<<NATOMS/2, 1024, 0, stream>>>(qkv, idxs, cutw, vecn, eA, Wswz,
                                                   beK, beV, s, o, vin, vout, l);
    }
    final_kernel<<<NATOMS, 128, 0, stream>>>(o, lng, lnb, Wo1, Wo2, batch, perm, hout);
    reduce_kernel<<<1, 1024, 0, stream>>>(hout, out);
}